// Round 1
// baseline (250.219 us; speedup 1.0000x reference)
//
#include <hip/hip_runtime.h>

// RWKV-7 DPLR single-step decode: B=64, H=32, K=V=128, fp32.
// Per (b,h): s = a^T H0 ; t = (q*g)^T H0 ; alpha=q.b ; beta=q.k
//            o = t + alpha*s + beta*v ; Ht = diag(g)H0 + b s^T + k v^T
// Columns of H are independent -> each thread owns 4 cols x 16 rows of H
// in registers (16 x float4). H is read once, Ht written once. Memory-bound.

#define KD 128
#define VD 128
#define BH_TOTAL 2048   // B*H = 64*32

__global__ __launch_bounds__(256) void dplr_decode_t1_kernel(
    const float* __restrict__ q_,  const float* __restrict__ k_,
    const float* __restrict__ v_,  const float* __restrict__ a_,
    const float* __restrict__ b_,  const float* __restrict__ gk_,
    const float* __restrict__ h0_, float* __restrict__ out_)
{
    const int bh  = blockIdx.x;          // 0..2047  (b*H + h)
    const int tid = threadIdx.x;         // 0..255
    const int c4  = (tid & 31) * 4;      // column base, 0..124
    const int grp = tid >> 5;            // row group 0..7
    const int r0  = grp * 16;            // row base

    const size_t vec_off = (size_t)bh * KD;
    const size_t h_off   = (size_t)bh * (KD * VD);

    __shared__ float qs[KD], ks[KD], bs[KD], as_[KD], gs[KD], qgs[KD];
    __shared__ float sred[8][VD];
    __shared__ float tred[8][VD];
    __shared__ float scomb[VD];
    __shared__ float red2[2];            // [0]=alpha, [1]=beta

    // ---- issue H loads early (consumed after first sync) ----
    float4 Hreg[16];
    const float* hp = h0_ + h_off + (size_t)r0 * VD + c4;
#pragma unroll
    for (int j = 0; j < 16; ++j) {
        Hreg[j] = *(const float4*)(hp + (size_t)j * VD);
    }

    // v for my 4 columns (used in Ht and nowhere else per-lane)
    const float4 v4 = *(const float4*)(v_ + vec_off + c4);

    // ---- stage small per-(b,h) vectors into LDS ----
    if (tid < KD) {
        float qq = q_[vec_off + tid];
        float gg = expf(gk_[vec_off + tid]);
        qs[tid]  = qq;
        ks[tid]  = k_[vec_off + tid];
        bs[tid]  = b_[vec_off + tid];
        as_[tid] = a_[vec_off + tid];
        gs[tid]  = gg;
        qgs[tid] = qq * gg;
    }
    __syncthreads();

    // ---- alpha = q.b (wave 0), beta = q.k (wave 1) ----
    if (tid < 64) {
        float p = qs[tid] * bs[tid] + qs[tid + 64] * bs[tid + 64];
#pragma unroll
        for (int o = 32; o > 0; o >>= 1) p += __shfl_down(p, o, 64);
        if (tid == 0) red2[0] = p;
    } else if (tid < 128) {
        int l = tid - 64;
        float p = qs[l] * ks[l] + qs[l + 64] * ks[l + 64];
#pragma unroll
        for (int o = 32; o > 0; o >>= 1) p += __shfl_down(p, o, 64);
        if (l == 0) red2[1] = p;
    }

    // ---- partial s/t over my 16 rows (a[r], qg[r] are wave-uniform broadcasts) ----
    float4 sp = make_float4(0.f, 0.f, 0.f, 0.f);
    float4 tp = make_float4(0.f, 0.f, 0.f, 0.f);
#pragma unroll
    for (int j = 0; j < 16; ++j) {
        const float av = as_[r0 + j];
        const float qg = qgs[r0 + j];
        const float4 h = Hreg[j];
        sp.x += av * h.x; sp.y += av * h.y; sp.z += av * h.z; sp.w += av * h.w;
        tp.x += qg * h.x; tp.y += qg * h.y; tp.z += qg * h.z; tp.w += qg * h.w;
    }
    *(float4*)&sred[grp][c4] = sp;
    *(float4*)&tred[grp][c4] = tp;
    __syncthreads();

    // ---- combine partials; write o ----
    if (tid < VD) {
        float sc = 0.f, tc = 0.f;
#pragma unroll
        for (int g = 0; g < 8; ++g) { sc += sred[g][tid]; tc += tred[g][tid]; }
        scomb[tid] = sc;
        const float vv = v_[vec_off + tid];
        out_[(size_t)bh * VD + tid] = tc + red2[0] * sc + red2[1] * vv;
    }
    __syncthreads();

    // ---- Ht = g*H + b s^T + k v^T, written from registers ----
    const float4 s4 = *(const float4*)&scomb[c4];
    float* op = out_ + (size_t)BH_TOTAL * VD + h_off + (size_t)r0 * VD + c4;
#pragma unroll
    for (int j = 0; j < 16; ++j) {
        const int r = r0 + j;
        const float gr = gs[r];
        const float br = bs[r];
        const float kr = ks[r];
        const float4 h = Hreg[j];
        float4 o4;
        o4.x = gr * h.x + br * s4.x + kr * v4.x;
        o4.y = gr * h.y + br * s4.y + kr * v4.y;
        o4.z = gr * h.z + br * s4.z + kr * v4.z;
        o4.w = gr * h.w + br * s4.w + kr * v4.w;
        *(float4*)(op + (size_t)j * VD) = o4;
    }
}

extern "C" void kernel_launch(void* const* d_in, const int* in_sizes, int n_in,
                              void* d_out, int out_size, void* d_ws, size_t ws_size,
                              hipStream_t stream) {
    const float* q  = (const float*)d_in[0];
    const float* k  = (const float*)d_in[1];
    const float* v  = (const float*)d_in[2];
    const float* a  = (const float*)d_in[3];
    const float* b  = (const float*)d_in[4];
    const float* gk = (const float*)d_in[5];
    const float* h0 = (const float*)d_in[6];
    float* out = (float*)d_out;

    dplr_decode_t1_kernel<<<BH_TOTAL, 256, 0, stream>>>(q, k, v, a, b, gk, h0, out);
}